// Round 3
// baseline (2198.932 us; speedup 1.0000x reference)
//
#include <hip/hip_runtime.h>

typedef __bf16 bf16x8 __attribute__((ext_vector_type(8)));
typedef float f32x4 __attribute__((ext_vector_type(4)));
typedef unsigned short ushort_t;
typedef unsigned short u16x8 __attribute__((ext_vector_type(8)));

#define BSZ 4096
#define HID 1024
#define INPD 512
#define NSPAN 8
#define NOUT 2
#define NDAYS 20
#define XLD 1536  // X = [inp(512) | h(1024)] leading dim

__device__ __forceinline__ ushort_t f2bf(float f) {
  union { float f; unsigned u; } v; v.f = f;
  unsigned r = v.u + 0x7FFFu + ((v.u >> 16) & 1u);
  return (ushort_t)(r >> 16);
}
__device__ __forceinline__ float bf2f(ushort_t b) {
  union { unsigned u; float f; } v; v.u = ((unsigned)b) << 16;
  return v.f;
}
__device__ __forceinline__ float sigf(float x) { return 1.f / (1.f + __expf(-x)); }
__device__ __forceinline__ float tanhfast(float x) { return 2.f / (1.f + __expf(-2.f * x)) - 1.f; }

__device__ __forceinline__ void gload16(const void* g, void* l) {
  __builtin_amdgcn_global_load_lds((const __attribute__((address_space(1))) void*)g,
                                   (__attribute__((address_space(3))) void*)l, 16, 0, 0);
}

// ---------------------------------------------------------------------------
// Weight prep: Wg[r][c] bf16, r = (j/16)*64 + gate*16 + (j%16), c = [W_ih | W_hh]
// so a 64-wide N-group holds gates i,f,g,o for 16 consecutive hidden units.
// ---------------------------------------------------------------------------
__global__ void prep_gates_w(const float* __restrict__ Wih, const float* __restrict__ Whh,
                             const float* __restrict__ bih, const float* __restrict__ bhh,
                             ushort_t* __restrict__ Wg, float* __restrict__ bg) {
  int gid = blockIdx.x * 256 + threadIdx.x;  // over 4096*1536
  int r = gid / XLD;
  int cc = gid - r * XLD;
  int g = (r >> 4) & 3;
  int j = (r >> 6) * 16 + (r & 15);
  int src = g * HID + j;
  float v = (cc < INPD) ? Wih[(size_t)src * INPD + cc] : Whh[(size_t)src * HID + (cc - INPD)];
  Wg[gid] = f2bf(v);
  if (cc == 0) bg[r] = bih[src] + bhh[src];
}

__global__ void prep_fcin_w(const float* __restrict__ W, ushort_t* __restrict__ Wo) {
  int gid = blockIdx.x * 256 + threadIdx.x;  // over 512*1024
  Wo[gid] = f2bf(W[gid]);
}

// X_A = [0 | bf16(hx)], c = cx
__global__ void init_kernel(const float* __restrict__ hx, const float* __restrict__ cx,
                            ushort_t* __restrict__ X, float* __restrict__ c) {
  int gid = blockIdx.x * 256 + threadIdx.x;  // over 4096*1024
  int b = gid >> 10, j = gid & 1023;
  X[(size_t)b * XLD + INPD + j] = f2bf(hx[gid]);
  if (j < INPD) X[(size_t)b * XLD + j] = 0;
  c[gid] = cx[gid];
}

// num_spans = softmax(hx @ W_span.T + b_span), fp32
__global__ void span_kernel(const float* __restrict__ hx, const float* __restrict__ Wspan,
                            const float* __restrict__ bspan, float* __restrict__ out) {
  int gid = blockIdx.x * 256 + threadIdx.x;  // over 4096*8
  int b = gid >> 3, o = gid & 7;
  const float4* hr = (const float4*)(hx + (size_t)b * HID);
  const float4* wr = (const float4*)(Wspan + (size_t)o * HID);
  float acc = 0.f;
  for (int i = 0; i < HID / 4; ++i) {
    float4 h = hr[i], w = wr[i];
    acc += h.x * w.x + h.y * w.y + h.z * w.z + h.w * w.w;
  }
  acc += bspan[o];
  float m = acc;
  for (int s = 1; s < 8; s <<= 1) m = fmaxf(m, __shfl_xor(m, s));
  float e = __expf(acc - m);
  float ssum = e;
  for (int s = 1; s < 8; s <<= 1) ssum += __shfl_xor(ssum, s);
  out[gid] = e / ssum;
}

// out[b][t][:] = softmax(h_b @ W_fcout.T + b_fcout); one wave per row
__global__ void fcout_kernel(const ushort_t* __restrict__ X, const float* __restrict__ W,
                             const float* __restrict__ bvec, float* __restrict__ outp, int t) {
  const int lane = threadIdx.x & 63;
  const int wave = threadIdx.x >> 6;
  const int b = blockIdx.x * 4 + wave;
  const ushort_t* h = X + (size_t)b * XLD + INPD + lane * 16;
  u16x8 h0 = *(const u16x8*)(h);
  u16x8 h1 = *(const u16x8*)(h + 8);
  const float* w0 = W + lane * 16;
  const float* w1 = W + HID + lane * 16;
  float l0 = 0.f, l1 = 0.f;
#pragma unroll
  for (int j = 0; j < 8; ++j) {
    float ha = bf2f(h0[j]);
    l0 += ha * w0[j];
    l1 += ha * w1[j];
    float hb = bf2f(h1[j]);
    l0 += hb * w0[j + 8];
    l1 += hb * w1[j + 8];
  }
#pragma unroll
  for (int s = 32; s > 0; s >>= 1) {
    l0 += __shfl_xor(l0, s);
    l1 += __shfl_xor(l1, s);
  }
  if (lane == 0) {
    l0 += bvec[0];
    l1 += bvec[1];
    float m = fmaxf(l0, l1);
    float e0 = __expf(l0 - m), e1 = __expf(l1 - m);
    float inv = 1.f / (e0 + e1);
    float* o = outp + (size_t)b * (NDAYS * NOUT) + t * NOUT;
    o[0] = e0 * inv;
    o[1] = e1 * inv;
  }
}

// ---------------------------------------------------------------------------
// Gates GEMM, 256x256 tile, BK=64, 8 waves (2M x 4N), double-buffered LDS with
// frag-linear layout (zero-conflict ds_read_b128) + counted-vmcnt prefetch.
// C[m][n] = sum_k X[m][k] * Wg[n][k]; fused LSTM cell epilogue.
//
// LDS layout per buffer/operand: 32 frags of 1KB. Frag f = kk*16 + r holds the
// mfma_16x16x32 fragment for rows [r*16,r*16+16), k-slice [kk*32,kk*32+32):
// 16B slot (f*64 + li) holds row r*16+(li&15), k = kk*32+(li>>4)*8 .. +8.
// gload_lds writes linearly (slot = j*512 + tid), so the GLOBAL source address
// per lane implements the permutation (rule #21: linear dest, permuted src).
// ---------------------------------------------------------------------------
__global__ __launch_bounds__(512, 2) void gates256_kernel(
    const ushort_t* __restrict__ A, const ushort_t* __restrict__ B,
    const float* __restrict__ bias, float* __restrict__ cbuf,
    ushort_t* __restrict__ hout) {
  __shared__ __align__(16) ushort_t ldsA[2][16384];
  __shared__ __align__(16) ushort_t ldsB[2][16384];
  const int tid = threadIdx.x;
  const int lane = tid & 63;
  const int wave = tid >> 6;
  const int wmi = wave >> 2;  // 0..1 -> 128 rows
  const int wni = wave & 3;   // 0..3 -> 64 cols

  // XCD-aware bijective swizzle over 256 blocks (cpx = 32)
  const int bid = blockIdx.y * 16 + blockIdx.x;
  const int swz = (bid & 7) * 32 + (bid >> 3);
  const int bm = (swz & 15) * 256;
  const int bn = (swz >> 4) * 256;

  // staging source pointers: round j stages frags 8j..8j+7 (one per wave)
  const ushort_t* gA[4];
  const ushort_t* gB[4];
  int ldsOff[4];
#pragma unroll
  for (int j = 0; j < 4; ++j) {
    const int f = j * 8 + wave;
    const int kk = f >> 4, r = f & 15;
    const int row = r * 16 + (lane & 15);
    const int kc = kk * 32 + ((lane >> 4) << 3);
    gA[j] = A + (size_t)(bm + row) * XLD + kc;
    gB[j] = B + (size_t)(bn + row) * XLD + kc;
    ldsOff[j] = j * 4096 + wave * 512;  // ushort units: slot (j*512+wave*64)*8
  }

  f32x4 acc[8][4] = {};

  // prologue: stage tiles 0 and 1; wait tile 0 (vmcnt(8): tile 1 in flight)
#pragma unroll
  for (int j = 0; j < 4; ++j) {
    gload16(gA[j], &ldsA[0][ldsOff[j]]);
    gload16(gB[j], &ldsB[0][ldsOff[j]]);
  }
#pragma unroll
  for (int j = 0; j < 4; ++j) {
    gload16(gA[j] + 64, &ldsA[1][ldsOff[j]]);
    gload16(gB[j] + 64, &ldsB[1][ldsOff[j]]);
  }
  asm volatile("s_waitcnt vmcnt(8)" ::: "memory");
  __builtin_amdgcn_s_barrier();

  for (int t = 0; t < 24; ++t) {  // K = 24 * 64 = 1536
    const int cur = t & 1;
    const ushort_t* lA = ldsA[cur];
    const ushort_t* lB = ldsB[cur];
    bf16x8 bfr[2][4];
#pragma unroll
    for (int kk = 0; kk < 2; ++kk)
#pragma unroll
      for (int n = 0; n < 4; ++n)
        bfr[kk][n] = *(const bf16x8*)(lB + (kk * 16 + wni * 4 + n) * 512 + lane * 8);
#pragma unroll
    for (int m = 0; m < 8; ++m) {
      bf16x8 a0 = *(const bf16x8*)(lA + (wmi * 8 + m) * 512 + lane * 8);
      bf16x8 a1 = *(const bf16x8*)(lA + (16 + wmi * 8 + m) * 512 + lane * 8);
      __builtin_amdgcn_s_setprio(1);
#pragma unroll
      for (int n = 0; n < 4; ++n)
        acc[m][n] = __builtin_amdgcn_mfma_f32_16x16x32_bf16(a0, bfr[0][n], acc[m][n], 0, 0, 0);
#pragma unroll
      for (int n = 0; n < 4; ++n)
        acc[m][n] = __builtin_amdgcn_mfma_f32_16x16x32_bf16(a1, bfr[1][n], acc[m][n], 0, 0, 0);
      __builtin_amdgcn_s_setprio(0);
    }
    if (t == 23) break;
    // all waves' reads of buf[cur] are complete (lgkm consumed by MFMA issue)
    __builtin_amdgcn_s_barrier();
    asm volatile("" ::: "memory");
    if (t + 2 < 24) {
      const int k0 = (t + 2) * 64;
#pragma unroll
      for (int j = 0; j < 4; ++j) {
        gload16(gA[j] + k0, &ldsA[cur][ldsOff[j]]);
        gload16(gB[j] + k0, &ldsB[cur][ldsOff[j]]);
      }
      asm volatile("s_waitcnt vmcnt(8)" ::: "memory");  // tile t+1 landed
    } else {
      asm volatile("s_waitcnt vmcnt(0)" ::: "memory");  // drain old tail loads
    }
    __builtin_amdgcn_s_barrier();
  }

  // fused LSTM epilogue: 64-col group = gates i,f,g,o for 16 hidden units
  const int colbase = bn + wni * 64;
  const int jj = (colbase >> 6) * 16 + (lane & 15);
  const int cb = colbase + (lane & 15);
  const float bI = bias[cb];
  const float bF = bias[cb + 16];
  const float bG = bias[cb + 32];
  const float bO = bias[cb + 48];
#pragma unroll
  for (int m = 0; m < 8; ++m) {
#pragma unroll
    for (int r = 0; r < 4; ++r) {
      const int b = bm + wmi * 128 + m * 16 + ((lane >> 4) << 2) + r;
      float ig = sigf(acc[m][0][r] + bI);
      float fg = sigf(acc[m][1][r] + bF);
      float gg = tanhfast(acc[m][2][r] + bG);
      float og = sigf(acc[m][3][r] + bO);
      size_t cidx = (size_t)b * HID + jj;
      float cn = fg * cbuf[cidx] + ig * gg;
      cbuf[cidx] = cn;
      hout[(size_t)b * XLD + INPD + jj] = f2bf(og * tanhfast(cn));
    }
  }
}

// ---------------------------------------------------------------------------
// fcin GEMM (m97-style 128x128, BK=32): C = relu(h @ Wfc^T + b) -> bf16 X cols
// ---------------------------------------------------------------------------
__global__ void gemm_fcin(const ushort_t* __restrict__ A, int lda,
                          const ushort_t* __restrict__ B, int ldb, int K,
                          const float* __restrict__ bias, ushort_t* __restrict__ hout) {
  __shared__ __align__(16) ushort_t ldsA[128 * 32];
  __shared__ __align__(16) ushort_t ldsB[128 * 32];
  const int tid = threadIdx.x;
  const int lane = tid & 63;
  const int wave = tid >> 6;

  int bid = blockIdx.y * gridDim.x + blockIdx.x;
  int nwg = gridDim.x * gridDim.y;
  int cpx = nwg >> 3;
  int swz = (bid & 7) * cpx + (bid >> 3);
  int bx = swz % gridDim.x;
  int by = swz / gridDim.x;
  const int bm = bx * 128;
  const int bn = by * 128;
  const int wm = (wave >> 1) * 64;
  const int wn = (wave & 1) * 64;

  f32x4 acc[4][4] = {};

  const ushort_t* gAw = A + (size_t)(bm + wave * 32 + (lane >> 2)) * lda + (lane & 3) * 8;
  const ushort_t* gBw = B + (size_t)(bn + wave * 32 + (lane >> 2)) * ldb + (lane & 3) * 8;
  ushort_t* lA = ldsA + wave * 32 * 32;
  ushort_t* lB = ldsB + wave * 32 * 32;

  for (int k0 = 0; k0 < K; k0 += 32) {
    gload16(gAw + k0, lA);
    gload16(gAw + 16 * lda + k0, lA + 512);
    gload16(gBw + k0, lB);
    gload16(gBw + 16 * ldb + k0, lB + 512);
    __syncthreads();

    bf16x8 af[4], bf[4];
    const int q = lane >> 4;
#pragma unroll
    for (int i = 0; i < 4; ++i) {
      int ar = wm + i * 16 + (lane & 15);
      af[i] = *(const bf16x8*)(ldsA + ar * 32 + q * 8);
      int br = wn + i * 16 + (lane & 15);
      bf[i] = *(const bf16x8*)(ldsB + br * 32 + q * 8);
    }
#pragma unroll
    for (int mi = 0; mi < 4; ++mi)
#pragma unroll
      for (int ni = 0; ni < 4; ++ni)
        acc[mi][ni] = __builtin_amdgcn_mfma_f32_16x16x32_bf16(af[mi], bf[ni], acc[mi][ni], 0, 0, 0);
    __syncthreads();
  }

#pragma unroll
  for (int mi = 0; mi < 4; ++mi) {
#pragma unroll
    for (int ni = 0; ni < 4; ++ni) {
      const int n = bn + wn + ni * 16 + (lane & 15);
      const float bb = bias[n];
#pragma unroll
      for (int r = 0; r < 4; ++r) {
        const int b = bm + wm + mi * 16 + ((lane >> 4) << 2) + r;
        float v = fmaxf(acc[mi][ni][r] + bb, 0.f);
        hout[(size_t)b * XLD + n] = f2bf(v);
      }
    }
  }
}

extern "C" void kernel_launch(void* const* d_in, const int* in_sizes, int n_in, void* d_out,
                              int out_size, void* d_ws, size_t ws_size, hipStream_t stream) {
  const float* hx = (const float*)d_in[0];
  const float* cx = (const float*)d_in[1];
  const float* Wih = (const float*)d_in[2];
  const float* Whh = (const float*)d_in[3];
  const float* bih = (const float*)d_in[4];
  const float* bhh = (const float*)d_in[5];
  const float* Wfcin = (const float*)d_in[6];
  const float* bfcin = (const float*)d_in[7];
  const float* Wfcout = (const float*)d_in[8];
  const float* bfcout = (const float*)d_in[9];
  const float* Wspan = (const float*)d_in[10];
  const float* bspan = (const float*)d_in[11];
  float* out = (float*)d_out;

  char* ws = (char*)d_ws;
  ushort_t* Wg = (ushort_t*)(ws);                // 4096*1536*2 = 12582912
  ushort_t* Wfc = (ushort_t*)(ws + 12582912);    // 512*1024*2  =  1048576
  float* bg = (float*)(ws + 13631488);           // 4096*4      =    16384
  ushort_t* XA = (ushort_t*)(ws + 13647872);     // 12582912
  ushort_t* XB = (ushort_t*)(ws + 26230784);     // 12582912
  float* cbuf = (float*)(ws + 38813696);         // 16777216 -> total 55590912 B

  prep_gates_w<<<(BSZ * XLD) / 256, 256, 0, stream>>>(Wih, Whh, bih, bhh, Wg, bg);
  prep_fcin_w<<<(INPD * HID) / 256, 256, 0, stream>>>(Wfcin, Wfc);
  init_kernel<<<(BSZ * HID) / 256, 256, 0, stream>>>(hx, cx, XA, cbuf);
  span_kernel<<<(BSZ * NSPAN) / 256, 256, 0, stream>>>(hx, Wspan, bspan, out);

  for (int t = 0; t < NDAYS; ++t) {
    ushort_t* Xin = (t & 1) ? XB : XA;
    ushort_t* Xout = (t & 1) ? XA : XB;
    gates256_kernel<<<dim3(16, 16), 512, 0, stream>>>(Xin, Wg, bg, cbuf, Xout);
    fcout_kernel<<<BSZ / 4, 256, 0, stream>>>(Xout, Wfcout, bfcout, out + BSZ * NSPAN, t);
    if (t < NDAYS - 1)
      gemm_fcin<<<dim3(32, 4), 256, 0, stream>>>(Xout + INPD, XLD, Wfc, HID, HID, bfcin, Xout);
  }
}

// Round 4
// 2159.883 us; speedup vs baseline: 1.0181x; 1.0181x over previous
//
#include <hip/hip_runtime.h>

typedef __bf16 bf16x8 __attribute__((ext_vector_type(8)));
typedef float f32x4 __attribute__((ext_vector_type(4)));
typedef unsigned short ushort_t;
typedef unsigned short u16x8 __attribute__((ext_vector_type(8)));

#define BSZ 4096
#define HID 1024
#define INPD 512
#define NSPAN 8
#define NOUT 2
#define NDAYS 20
#define XLD 1536  // X = [inp(512) | h(1024)] leading dim

__device__ __forceinline__ ushort_t f2bf(float f) {
  union { float f; unsigned u; } v; v.f = f;
  unsigned r = v.u + 0x7FFFu + ((v.u >> 16) & 1u);
  return (ushort_t)(r >> 16);
}
__device__ __forceinline__ float bf2f(ushort_t b) {
  union { unsigned u; float f; } v; v.u = ((unsigned)b) << 16;
  return v.f;
}
__device__ __forceinline__ float sigf(float x) { return 1.f / (1.f + __expf(-x)); }
__device__ __forceinline__ float tanhfast(float x) { return 2.f / (1.f + __expf(-2.f * x)) - 1.f; }

__device__ __forceinline__ void gload16(const void* g, void* l) {
  __builtin_amdgcn_global_load_lds((const __attribute__((address_space(1))) void*)g,
                                   (__attribute__((address_space(3))) void*)l, 16, 0, 0);
}

// ---------------------------------------------------------------------------
// Weight prep: Wg[r][c] bf16, r = (j/16)*64 + gate*16 + (j%16), c = [W_ih | W_hh]
// ---------------------------------------------------------------------------
__global__ void prep_gates_w(const float* __restrict__ Wih, const float* __restrict__ Whh,
                             const float* __restrict__ bih, const float* __restrict__ bhh,
                             ushort_t* __restrict__ Wg, float* __restrict__ bg) {
  int gid = blockIdx.x * 256 + threadIdx.x;  // over 4096*1536
  int r = gid / XLD;
  int cc = gid - r * XLD;
  int g = (r >> 4) & 3;
  int j = (r >> 6) * 16 + (r & 15);
  int src = g * HID + j;
  float v = (cc < INPD) ? Wih[(size_t)src * INPD + cc] : Whh[(size_t)src * HID + (cc - INPD)];
  Wg[gid] = f2bf(v);
  if (cc == 0) bg[r] = bih[src] + bhh[src];
}

__global__ void prep_fcin_w(const float* __restrict__ W, ushort_t* __restrict__ Wo) {
  int gid = blockIdx.x * 256 + threadIdx.x;  // over 512*1024
  Wo[gid] = f2bf(W[gid]);
}

// X_A = [0 | bf16(hx)], c = cx
__global__ void init_kernel(const float* __restrict__ hx, const float* __restrict__ cx,
                            ushort_t* __restrict__ X, float* __restrict__ c) {
  int gid = blockIdx.x * 256 + threadIdx.x;  // over 4096*1024
  int b = gid >> 10, j = gid & 1023;
  X[(size_t)b * XLD + INPD + j] = f2bf(hx[gid]);
  if (j < INPD) X[(size_t)b * XLD + j] = 0;
  c[gid] = cx[gid];
}

// num_spans = softmax(hx @ W_span.T + b_span), fp32
__global__ void span_kernel(const float* __restrict__ hx, const float* __restrict__ Wspan,
                            const float* __restrict__ bspan, float* __restrict__ out) {
  int gid = blockIdx.x * 256 + threadIdx.x;  // over 4096*8
  int b = gid >> 3, o = gid & 7;
  const float4* hr = (const float4*)(hx + (size_t)b * HID);
  const float4* wr = (const float4*)(Wspan + (size_t)o * HID);
  float acc = 0.f;
  for (int i = 0; i < HID / 4; ++i) {
    float4 h = hr[i], w = wr[i];
    acc += h.x * w.x + h.y * w.y + h.z * w.z + h.w * w.w;
  }
  acc += bspan[o];
  float m = acc;
  for (int s = 1; s < 8; s <<= 1) m = fmaxf(m, __shfl_xor(m, s));
  float e = __expf(acc - m);
  float ssum = e;
  for (int s = 1; s < 8; s <<= 1) ssum += __shfl_xor(ssum, s);
  out[gid] = e / ssum;
}

// out[b][t][:] = softmax(h_b @ W_fcout.T + b_fcout); one wave per row
__global__ void fcout_kernel(const ushort_t* __restrict__ X, const float* __restrict__ W,
                             const float* __restrict__ bvec, float* __restrict__ outp, int t) {
  const int lane = threadIdx.x & 63;
  const int wave = threadIdx.x >> 6;
  const int b = blockIdx.x * 4 + wave;
  const ushort_t* h = X + (size_t)b * XLD + INPD + lane * 16;
  u16x8 h0 = *(const u16x8*)(h);
  u16x8 h1 = *(const u16x8*)(h + 8);
  const float* w0 = W + lane * 16;
  const float* w1 = W + HID + lane * 16;
  float l0 = 0.f, l1 = 0.f;
#pragma unroll
  for (int j = 0; j < 8; ++j) {
    float ha = bf2f(h0[j]);
    l0 += ha * w0[j];
    l1 += ha * w1[j];
    float hb = bf2f(h1[j]);
    l0 += hb * w0[j + 8];
    l1 += hb * w1[j + 8];
  }
#pragma unroll
  for (int s = 32; s > 0; s >>= 1) {
    l0 += __shfl_xor(l0, s);
    l1 += __shfl_xor(l1, s);
  }
  if (lane == 0) {
    l0 += bvec[0];
    l1 += bvec[1];
    float m = fmaxf(l0, l1);
    float e0 = __expf(l0 - m), e1 = __expf(l1 - m);
    float inv = 1.f / (e0 + e1);
    float* o = outp + (size_t)b * (NDAYS * NOUT) + t * NOUT;
    o[0] = e0 * inv;
    o[1] = e1 * inv;
  }
}

// ---------------------------------------------------------------------------
// Gates GEMM, 256x256, BK=64, 8 waves (2Mx4N), frag-linear LDS (0-conflict),
// m201-style 8-phase schedule: per K-tile 4 phases, each
//   {frag ds_reads for quadrant; stage one operand of tile t+2; barrier;
//    setprio(1); 16 MFMA; setprio(0); barrier}
// vmcnt(8) once per K-tile (phase 4), never 0 in steady state.
// Hazards: B(t)-reads complete before P2-end barrier -> B(t+2) stage at P3 ok;
// A(t)-reads complete before P3-end barrier -> A(t+2) stage at P4 ok;
// per-wave vmcnt(8) before tile-end barrier -> tile t+1 landed chip-wide.
// ---------------------------------------------------------------------------
__global__ __launch_bounds__(512, 2) void gates256_kernel(
    const ushort_t* __restrict__ A, const ushort_t* __restrict__ B,
    const float* __restrict__ bias, float* __restrict__ cbuf,
    ushort_t* __restrict__ hout) {
  __shared__ __align__(16) ushort_t ldsA[2][16384];
  __shared__ __align__(16) ushort_t ldsB[2][16384];
  const int tid = threadIdx.x;
  const int lane = tid & 63;
  const int wave = tid >> 6;
  const int wmi = wave >> 2;  // 0..1 -> 128 rows
  const int wni = wave & 3;   // 0..3 -> 64 cols

  // XCD-aware bijective swizzle over 256 blocks (cpx = 32)
  const int bid = blockIdx.y * 16 + blockIdx.x;
  const int swz = (bid & 7) * 32 + (bid >> 3);
  const int bm = (swz & 15) * 256;
  const int bn = (swz >> 4) * 256;

  // staging source pointers: round j stages frags 8j..8j+7 (one per wave)
  // frag f = kk*16 + r: rows r*16..+16, k-slice kk*32..+32, lane li ->
  // row r*16+(li&15), k = kk*32+(li>>4)*8. LDS dest linear: slot j*512+tid.
  const ushort_t* gA[4];
  const ushort_t* gB[4];
  int ldsOff[4];
#pragma unroll
  for (int j = 0; j < 4; ++j) {
    const int f = j * 8 + wave;
    const int kk = f >> 4, r = f & 15;
    const int row = r * 16 + (lane & 15);
    const int kc = kk * 32 + ((lane >> 4) << 3);
    gA[j] = A + (size_t)(bm + row) * XLD + kc;
    gB[j] = B + (size_t)(bn + row) * XLD + kc;
    ldsOff[j] = j * 4096 + wave * 512;
  }

  f32x4 acc[8][4] = {};

  // prologue: stage tiles 0 and 1; vmcnt(8) -> tile 0 landed, tile 1 in flight
#pragma unroll
  for (int j = 0; j < 4; ++j) {
    gload16(gA[j], &ldsA[0][ldsOff[j]]);
    gload16(gB[j], &ldsB[0][ldsOff[j]]);
  }
#pragma unroll
  for (int j = 0; j < 4; ++j) {
    gload16(gA[j] + 64, &ldsA[1][ldsOff[j]]);
    gload16(gB[j] + 64, &ldsB[1][ldsOff[j]]);
  }
  asm volatile("s_waitcnt vmcnt(8)" ::: "memory");
  __builtin_amdgcn_sched_barrier(0);
  __builtin_amdgcn_s_barrier();

#pragma unroll 2
  for (int t = 0; t < 24; ++t) {  // K = 24 * 64 = 1536
    const int cur = t & 1;
    const ushort_t* lA = ldsA[cur];
    const ushort_t* lB = ldsB[cur];
    const bool stg = (t + 2 < 24);
    bf16x8 af[4][2];   // m-mod-4 x kk; reused P1 (m0-3) then P3 (m4-7)
    bf16x8 bfr[4][2];  // n x kk; all 8 live from P2 on

    // ---- Phase 1: reads A[m0-3], B[n0-1]; MFMA Q1
#pragma unroll
    for (int m = 0; m < 4; ++m)
#pragma unroll
      for (int kk = 0; kk < 2; ++kk)
        af[m][kk] = *(const bf16x8*)(lA + (kk * 16 + wmi * 8 + m) * 512 + lane * 8);
#pragma unroll
    for (int n = 0; n < 2; ++n)
#pragma unroll
      for (int kk = 0; kk < 2; ++kk)
        bfr[n][kk] = *(const bf16x8*)(lB + (kk * 16 + wni * 4 + n) * 512 + lane * 8);
    __builtin_amdgcn_s_barrier();
    __builtin_amdgcn_s_setprio(1);
#pragma unroll
    for (int m = 0; m < 4; ++m)
#pragma unroll
      for (int n = 0; n < 2; ++n)
#pragma unroll
        for (int kk = 0; kk < 2; ++kk)
          acc[m][n] = __builtin_amdgcn_mfma_f32_16x16x32_bf16(af[m][kk], bfr[n][kk], acc[m][n], 0, 0, 0);
    __builtin_amdgcn_s_setprio(0);
    __builtin_amdgcn_s_barrier();

    // ---- Phase 2: reads B[n2-3]; MFMA Q2
#pragma unroll
    for (int n = 2; n < 4; ++n)
#pragma unroll
      for (int kk = 0; kk < 2; ++kk)
        bfr[n][kk] = *(const bf16x8*)(lB + (kk * 16 + wni * 4 + n) * 512 + lane * 8);
    __builtin_amdgcn_s_barrier();
    __builtin_amdgcn_s_setprio(1);
#pragma unroll
    for (int m = 0; m < 4; ++m)
#pragma unroll
      for (int n = 2; n < 4; ++n)
#pragma unroll
        for (int kk = 0; kk < 2; ++kk)
          acc[m][n] = __builtin_amdgcn_mfma_f32_16x16x32_bf16(af[m][kk], bfr[n][kk], acc[m][n], 0, 0, 0);
    __builtin_amdgcn_s_setprio(0);
    __builtin_amdgcn_s_barrier();

    // ---- Phase 3: reads A[m4-7]; stage B(t+2); MFMA Q3
#pragma unroll
    for (int m = 0; m < 4; ++m)
#pragma unroll
      for (int kk = 0; kk < 2; ++kk)
        af[m][kk] = *(const bf16x8*)(lA + (kk * 16 + wmi * 8 + 4 + m) * 512 + lane * 8);
    if (stg) {
      const int k0 = (t + 2) * 64;
#pragma unroll
      for (int j = 0; j < 4; ++j) gload16(gB[j] + k0, &ldsB[cur][ldsOff[j]]);
    }
    __builtin_amdgcn_s_barrier();
    __builtin_amdgcn_s_setprio(1);
#pragma unroll
    for (int m = 0; m < 4; ++m)
#pragma unroll
      for (int n = 0; n < 2; ++n)
#pragma unroll
        for (int kk = 0; kk < 2; ++kk)
          acc[4 + m][n] = __builtin_amdgcn_mfma_f32_16x16x32_bf16(af[m][kk], bfr[n][kk], acc[4 + m][n], 0, 0, 0);
    __builtin_amdgcn_s_setprio(0);
    __builtin_amdgcn_s_barrier();

    // ---- Phase 4: stage A(t+2); MFMA Q4; vmcnt; tile-end barrier
    if (stg) {
      const int k0 = (t + 2) * 64;
#pragma unroll
      for (int j = 0; j < 4; ++j) gload16(gA[j] + k0, &ldsA[cur][ldsOff[j]]);
    }
    __builtin_amdgcn_s_barrier();
    __builtin_amdgcn_s_setprio(1);
#pragma unroll
    for (int m = 0; m < 4; ++m)
#pragma unroll
      for (int n = 2; n < 4; ++n)
#pragma unroll
        for (int kk = 0; kk < 2; ++kk)
          acc[4 + m][n] = __builtin_amdgcn_mfma_f32_16x16x32_bf16(af[m][kk], bfr[n][kk], acc[4 + m][n], 0, 0, 0);
    __builtin_amdgcn_s_setprio(0);
    if (stg) {
      asm volatile("s_waitcnt vmcnt(8)" ::: "memory");  // tile t+1 landed
    } else if (t == 22) {
      asm volatile("s_waitcnt vmcnt(0)" ::: "memory");  // drain tile 23
    }
    __builtin_amdgcn_sched_barrier(0);
    if (t < 23) __builtin_amdgcn_s_barrier();
  }

  // fused LSTM epilogue: 64-col group = gates i,f,g,o for 16 hidden units
  const int colbase = bn + wni * 64;
  const int jj = (colbase >> 6) * 16 + (lane & 15);
  const int cb = colbase + (lane & 15);
  const float bI = bias[cb];
  const float bF = bias[cb + 16];
  const float bG = bias[cb + 32];
  const float bO = bias[cb + 48];
#pragma unroll
  for (int m = 0; m < 8; ++m) {
#pragma unroll
    for (int r = 0; r < 4; ++r) {
      const int b = bm + wmi * 128 + m * 16 + ((lane >> 4) << 2) + r;
      float ig = sigf(acc[m][0][r] + bI);
      float fg = sigf(acc[m][1][r] + bF);
      float gg = tanhfast(acc[m][2][r] + bG);
      float og = sigf(acc[m][3][r] + bO);
      size_t cidx = (size_t)b * HID + jj;
      float cn = fg * cbuf[cidx] + ig * gg;
      cbuf[cidx] = cn;
      hout[(size_t)b * XLD + INPD + jj] = f2bf(og * tanhfast(cn));
    }
  }
}

// ---------------------------------------------------------------------------
// fcin GEMM (m97-style 128x128, BK=32): C = relu(h @ Wfc^T + b) -> bf16 X cols
// ---------------------------------------------------------------------------
__global__ void gemm_fcin(const ushort_t* __restrict__ A, int lda,
                          const ushort_t* __restrict__ B, int ldb, int K,
                          const float* __restrict__ bias, ushort_t* __restrict__ hout) {
  __shared__ __align__(16) ushort_t ldsA[128 * 32];
  __shared__ __align__(16) ushort_t ldsB[128 * 32];
  const int tid = threadIdx.x;
  const int lane = tid & 63;
  const int wave = tid >> 6;

  int bid = blockIdx.y * gridDim.x + blockIdx.x;
  int nwg = gridDim.x * gridDim.y;
  int cpx = nwg >> 3;
  int swz = (bid & 7) * cpx + (bid >> 3);
  int bx = swz % gridDim.x;
  int by = swz / gridDim.x;
  const int bm = bx * 128;
  const int bn = by * 128;
  const int wm = (wave >> 1) * 64;
  const int wn = (wave & 1) * 64;

  f32x4 acc[4][4] = {};

  const ushort_t* gAw = A + (size_t)(bm + wave * 32 + (lane >> 2)) * lda + (lane & 3) * 8;
  const ushort_t* gBw = B + (size_t)(bn + wave * 32 + (lane >> 2)) * ldb + (lane & 3) * 8;
  ushort_t* lA = ldsA + wave * 32 * 32;
  ushort_t* lB = ldsB + wave * 32 * 32;

  for (int k0 = 0; k0 < K; k0 += 32) {
    gload16(gAw + k0, lA);
    gload16(gAw + 16 * lda + k0, lA + 512);
    gload16(gBw + k0, lB);
    gload16(gBw + 16 * ldb + k0, lB + 512);
    __syncthreads();

    bf16x8 af[4], bf[4];
    const int q = lane >> 4;
#pragma unroll
    for (int i = 0; i < 4; ++i) {
      int ar = wm + i * 16 + (lane & 15);
      af[i] = *(const bf16x8*)(ldsA + ar * 32 + q * 8);
      int br = wn + i * 16 + (lane & 15);
      bf[i] = *(const bf16x8*)(ldsB + br * 32 + q * 8);
    }
#pragma unroll
    for (int mi = 0; mi < 4; ++mi)
#pragma unroll
      for (int ni = 0; ni < 4; ++ni)
        acc[mi][ni] = __builtin_amdgcn_mfma_f32_16x16x32_bf16(af[mi], bf[ni], acc[mi][ni], 0, 0, 0);
    __syncthreads();
  }

#pragma unroll
  for (int mi = 0; mi < 4; ++mi) {
#pragma unroll
    for (int ni = 0; ni < 4; ++ni) {
      const int n = bn + wn + ni * 16 + (lane & 15);
      const float bb = bias[n];
#pragma unroll
      for (int r = 0; r < 4; ++r) {
        const int b = bm + wm + mi * 16 + ((lane >> 4) << 2) + r;
        float v = fmaxf(acc[mi][ni][r] + bb, 0.f);
        hout[(size_t)b * XLD + n] = f2bf(v);
      }
    }
  }
}

extern "C" void kernel_launch(void* const* d_in, const int* in_sizes, int n_in, void* d_out,
                              int out_size, void* d_ws, size_t ws_size, hipStream_t stream) {
  const float* hx = (const float*)d_in[0];
  const float* cx = (const float*)d_in[1];
  const float* Wih = (const float*)d_in[2];
  const float* Whh = (const float*)d_in[3];
  const float* bih = (const float*)d_in[4];
  const float* bhh = (const float*)d_in[5];
  const float* Wfcin = (const float*)d_in[6];
  const float* bfcin = (const float*)d_in[7];
  const float* Wfcout = (const float*)d_in[8];
  const float* bfcout = (const float*)d_in[9];
  const float* Wspan = (const float*)d_in[10];
  const float* bspan = (const float*)d_in[11];
  float* out = (float*)d_out;

  char* ws = (char*)d_ws;
  ushort_t* Wg = (ushort_t*)(ws);                // 4096*1536*2 = 12582912
  ushort_t* Wfc = (ushort_t*)(ws + 12582912);    // 512*1024*2  =  1048576
  float* bg = (float*)(ws + 13631488);           // 4096*4      =    16384
  ushort_t* XA = (ushort_t*)(ws + 13647872);     // 12582912
  ushort_t* XB = (ushort_t*)(ws + 26230784);     // 12582912
  float* cbuf = (float*)(ws + 38813696);         // 16777216 -> total 55590912 B

  prep_gates_w<<<(BSZ * XLD) / 256, 256, 0, stream>>>(Wih, Whh, bih, bhh, Wg, bg);
  prep_fcin_w<<<(INPD * HID) / 256, 256, 0, stream>>>(Wfcin, Wfc);
  init_kernel<<<(BSZ * HID) / 256, 256, 0, stream>>>(hx, cx, XA, cbuf);
  span_kernel<<<(BSZ * NSPAN) / 256, 256, 0, stream>>>(hx, Wspan, bspan, out);

  for (int t = 0; t < NDAYS; ++t) {
    ushort_t* Xin = (t & 1) ? XB : XA;
    ushort_t* Xout = (t & 1) ? XA : XB;
    gates256_kernel<<<dim3(16, 16), 512, 0, stream>>>(Xin, Wg, bg, cbuf, Xout);
    fcout_kernel<<<BSZ / 4, 256, 0, stream>>>(Xout, Wfcout, bfcout, out + BSZ * NSPAN, t);
    if (t < NDAYS - 1)
      gemm_fcin<<<dim3(32, 4), 256, 0, stream>>>(Xout + INPD, XLD, Wfc, HID, HID, bfcin, Xout);
  }
}